// Round 3
// baseline (538.449 us; speedup 1.0000x reference)
//
#include <hip/hip_runtime.h>

// SuppAlignLayer: 4-level ROI Align, B=2, C=256, N=512 boxes/batch, OUT=7, SR=2.
// Output per level: (1024, 256, 7, 7) fp32, levels concatenated flat.
//
// v4 (this round):
//  - Fused single-launch NHWC transpose for all 4 levels (v3 used 4 serialized
//    launches, 64KB LDS tiles, scalar stores -> ~348us of the 533us total).
//    New: 32pos x 256ch tile (33KB -> 4 blocks/CU), float4 loads AND float4
//    stores (ds_read_b128 from 16B-aligned stride-260 rows).
//  - Gather split by channel-half (grid.z=2): obuf 50KB->25KB (+4.7KB metadata)
//    -> 5 blocks/CU (occupancy 29.7% -> ~60%), the latency-hiding the L2/L3
//    gather needs. Sample metadata (2 offsets + 4 weights) precomputed once per
//    block into LDS; bin loop reads it as wave-uniform broadcasts.

#define OUTSZ 7
#define NBIN  49
#define NSAMP 196
#define ROI_STRIDE 12544u
#define LVL_STRIDE 12845056u   // 1024 * 12544

typedef float f2v __attribute__((ext_vector_type(2)));
typedef float f4v __attribute__((ext_vector_type(4)));

// ---------------- workspace layout (floats) ----------------
// L0: off 0,         HW=60800
// L1: off 31129600,  HW=15200
// L2: off 38912000,  HW=3800
// L3: off 40857600,  HW=950    total 41,344,000 fl = 165,376,000 B
#define WS_BYTES 165376000ull

// ============================================================
// Fused NCHW -> NHWC for all levels. Tile: 32 positions x 256 channels.
// Block budget per batch: L0 1900, L1 475, L2 119, L3 30  (prefix 1900/2375/2494/2524)
__global__ __launch_bounds__(256)
void fused_to_nhwc(const float* __restrict__ f0, const float* __restrict__ f1,
                   const float* __restrict__ f2, const float* __restrict__ f3,
                   float* __restrict__ ws)
{
    __shared__ __align__(16) float tile[32 * 260];   // [pos][c], stride 260 (1040B, 16B-aligned)
    const int bx = blockIdx.x;
    const int b  = blockIdx.y;
    const int t  = threadIdx.x;

    const float* src; float* dst; int HW; int pb;
    if (bx < 1900)      { src = f0; dst = ws;             HW = 60800; pb = bx; }
    else if (bx < 2375) { src = f1; dst = ws + 31129600u; HW = 15200; pb = bx - 1900; }
    else if (bx < 2494) { src = f2; dst = ws + 38912000u; HW = 3800;  pb = bx - 2375; }
    else                { src = f3; dst = ws + 40857600u; HW = 950;   pb = bx - 2494; }

    src += (size_t)b * 256u * (size_t)HW;
    dst += (size_t)b * (size_t)HW * 256u;

    const int p0 = pb * 32;
    const int pg = (t & 7) * 4;       // local position base (f4 along HW)
    const int cb = t >> 3;            // channel sub-index 0..31

    #pragma unroll
    for (int i = 0; i < 8; ++i) {
        const int c   = i * 32 + cb;
        const int pos = p0 + pg;
        const float* sp = src + (size_t)c * HW + pos;
        if (pos + 3 < HW) {
            f4v v; __builtin_memcpy(&v, sp, 16);
            tile[(pg + 0) * 260 + c] = v.x;
            tile[(pg + 1) * 260 + c] = v.y;
            tile[(pg + 2) * 260 + c] = v.z;
            tile[(pg + 3) * 260 + c] = v.w;
        } else {
            #pragma unroll
            for (int j = 0; j < 4; ++j)
                if (pos + j < HW) tile[(pg + j) * 260 + c] = sp[j];
        }
    }
    __syncthreads();

    const int wv = t >> 6, l = t & 63;
    #pragma unroll
    for (int i = 0; i < 8; ++i) {
        const int pl = i * 4 + wv;            // local pos 0..31
        const int pp = p0 + pl;
        if (pp < HW) {
            const f4v v = *reinterpret_cast<const f4v*>(&tile[pl * 260 + 4 * l]);
            *reinterpret_cast<f4v*>(dst + (size_t)pp * 256u + 4 * l) = v;   // 1KB/wave coalesced
        }
    }
}

// ============================================================
// NHWC gather: block = (roi, level, chalf). 256 thr = 4 waves.
// Wave handles bins wv, wv+4, ...; lane owns 2 channels (chalf*128 + 2l, +1).
__global__ __launch_bounds__(256)
void roi_gather_nhwc(const float* __restrict__ ws, const float* __restrict__ boxes,
                     float* __restrict__ out)
{
    __shared__ int   sO0[NSAMP], sO1[NSAMP];
    __shared__ float sW0[NSAMP], sW1[NSAMP], sW2[NSAMP], sW3[NSAMP];
    __shared__ float obuf[NBIN * 129];   // [bin][c_local], stride 129 (odd -> conflict-free readout)

    const int r     = blockIdx.x;
    const int lvl   = blockIdx.y;
    const int chalf = blockIdx.z;
    const int t  = threadIdx.x;
    const int wv = t >> 6, l = t & 63;

    int H, W; float scale; size_t off;
    switch (lvl) {
      case 0:  H = 200; W = 304; scale = 0.25f;    off = 0u;        break;
      case 1:  H = 100; W = 152; scale = 0.125f;   off = 31129600u; break;
      case 2:  H = 50;  W = 76;  scale = 0.0625f;  off = 38912000u; break;
      default: H = 25;  W = 38;  scale = 0.03125f; off = 40857600u; break;
    }
    const int HW = H * W;
    const int b  = r >> 9;

    if (t < NSAMP) {
        const float bx1 = boxes[r * 4 + 0] * scale;
        const float by1 = boxes[r * 4 + 1] * scale;
        const float bx2 = boxes[r * 4 + 2] * scale;
        const float by2 = boxes[r * 4 + 3] * scale;
        const float rw  = fmaxf(bx2 - bx1, 1.0f);
        const float rh  = fmaxf(by2 - by1, 1.0f);

        const int bin = t >> 2, sub = t & 3;
        const int ph = bin / 7, pw = bin % 7;
        const int ky = 2 * ph + (sub >> 1);
        const int kx = 2 * pw + (sub & 1);

        const float ys = by1 + (rh * (1.0f / 7.0f)) * (((float)ky + 0.5f) * 0.5f);
        const float xs = bx1 + (rw * (1.0f / 7.0f)) * (((float)kx + 0.5f) * 0.5f);

        const float Hf = (float)H, Wf = (float)W;
        const bool vy = (ys >= -1.0f) && (ys <= Hf);
        const bool vx = (xs >= -1.0f) && (xs <= Wf);

        const float yc = fminf(fmaxf(ys, 0.0f), Hf - 1.0f);
        const float xc = fminf(fmaxf(xs, 0.0f), Wf - 1.0f);
        const int y0 = (int)yc;
        const int x0 = (int)xc;
        const int y1i = min(y0 + 1, H - 1);
        const float ly = yc - (float)y0, lx = xc - (float)x0;
        const float hy = 1.0f - ly, hx = 1.0f - lx;

        int px; float wxA, wxB;
        if (x0 < W - 1) { px = x0;     wxA = hx;   wxB = lx;   }
        else            { px = W - 2;  wxA = 0.0f; wxB = 1.0f; }

        const float vm = (vy && vx) ? 0.25f : 0.0f;

        sO0[t] = (y0  * W + px) * 256;     // NHWC float offset of (row, px)
        sO1[t] = (y1i * W + px) * 256;
        sW0[t] = hy * wxA * vm;
        sW1[t] = hy * wxB * vm;
        sW2[t] = ly * wxA * vm;
        sW3[t] = ly * wxB * vm;
    }
    __syncthreads();

    const float* base = ws + off + (size_t)b * (size_t)HW * 256u
                         + (size_t)(chalf * 128 + 2 * l);

    #pragma unroll 1
    for (int bin = wv; bin < NBIN; bin += 4) {
        f2v acc = {0.0f, 0.0f};
        #pragma unroll
        for (int sub = 0; sub < 4; ++sub) {
            const int s = bin * 4 + sub;
            const int o0 = sO0[s], o1 = sO1[s];          // wave-uniform broadcasts
            const float w00 = sW0[s], w01 = sW1[s], w10 = sW2[s], w11 = sW3[s];
            f2v a0, b0, a1, b1;
            __builtin_memcpy(&a0, base + o0,       8);   // 512B/wave coalesced
            __builtin_memcpy(&b0, base + o0 + 256, 8);
            __builtin_memcpy(&a1, base + o1,       8);
            __builtin_memcpy(&b1, base + o1 + 256, 8);
            acc += a0 * w00 + b0 * w01 + a1 * w10 + b1 * w11;
        }
        obuf[bin * 129 + 2 * l]     = acc.x;   // stride-2 lanes: 2-way (free)
        obuf[bin * 129 + 2 * l + 1] = acc.y;
    }
    __syncthreads();

    float* o = out + (size_t)lvl * LVL_STRIDE + (size_t)r * ROI_STRIDE
                   + (size_t)chalf * 6272u;
    #pragma unroll 1
    for (int k = 0; k < 24; ++k) {
        const int item = k * 256 + t;                    // item = c_local*49 + bin
        const unsigned c = (unsigned)item / 49u;
        const int bin = item - (int)c * 49;
        o[item] = obuf[bin * 129 + (int)c];              // consecutive banks
    }
    if (t < 128) {
        const int item = 6144 + t;
        const unsigned c = (unsigned)item / 49u;
        const int bin = item - (int)c * 49;
        o[item] = obuf[bin * 129 + (int)c];
    }
}

// ============================================================
// v2 fallback (scattered NCHW gather) — used only if ws too small.
__device__ __forceinline__ f2v load_f2(const float* p) {
    f2v v; __builtin_memcpy(&v, p, 8); return v;
}

__global__ __launch_bounds__(256)
void roi_align_all_levels(const float* __restrict__ f0,
                          const float* __restrict__ f1,
                          const float* __restrict__ f2,
                          const float* __restrict__ f3,
                          const float* __restrict__ boxes,
                          float* __restrict__ out)
{
    __shared__ int   sD0[NSAMP];
    __shared__ int   sD1[NSAMP];
    __shared__ float sW0[NSAMP];
    __shared__ float sW1[NSAMP];
    __shared__ float sW2[NSAMP];
    __shared__ float sW3[NSAMP];

    const int r   = blockIdx.x;
    const int lvl = blockIdx.y;
    const int t   = threadIdx.x;

    int H, W; float scale; const float* feat;
    switch (lvl) {
      case 0:  H = 200; W = 304; scale = 0.25f;    feat = f0; break;
      case 1:  H = 100; W = 152; scale = 0.125f;   feat = f1; break;
      case 2:  H = 50;  W = 76;  scale = 0.0625f;  feat = f2; break;
      default: H = 25;  W = 38;  scale = 0.03125f; feat = f3; break;
    }
    const unsigned HW = (unsigned)(H * W);
    const int b = r >> 9;

    if (t < NSAMP) {
        const float bx1 = boxes[r * 4 + 0] * scale;
        const float by1 = boxes[r * 4 + 1] * scale;
        const float bx2 = boxes[r * 4 + 2] * scale;
        const float by2 = boxes[r * 4 + 3] * scale;
        const float rw  = fmaxf(bx2 - bx1, 1.0f);
        const float rh  = fmaxf(by2 - by1, 1.0f);

        const int bin = t >> 2, sub = t & 3;
        const int ph = bin / 7, pw = bin % 7;
        const int ky = 2 * ph + (sub >> 1);
        const int kx = 2 * pw + (sub & 1);

        const float gy = ((float)ky + 0.5f) * 0.5f;
        const float gx = ((float)kx + 0.5f) * 0.5f;
        const float ys = by1 + (rh / 7.0f) * gy;
        const float xs = bx1 + (rw / 7.0f) * gx;

        const float Hf = (float)H, Wf = (float)W;
        const bool vy = (ys >= -1.0f) && (ys <= Hf);
        const bool vx = (xs >= -1.0f) && (xs <= Wf);

        const float yc = fminf(fmaxf(ys, 0.0f), Hf - 1.0f);
        const float xc = fminf(fmaxf(xs, 0.0f), Wf - 1.0f);
        const int y0 = (int)yc;
        const int x0 = (int)xc;
        const int y1i = min(y0 + 1, H - 1);
        const float ly = yc - (float)y0, lx = xc - (float)x0;
        const float hy = 1.0f - ly, hx = 1.0f - lx;

        int px; float wxA, wxB;
        if (x0 < W - 1) { px = x0;     wxA = hx;   wxB = lx;   }
        else            { px = W - 2;  wxA = 0.0f; wxB = 1.0f; }

        const float vm = (vy && vx) ? 0.25f : 0.0f;

        const int s = sub * NBIN + bin;
        sD0[s] = y0  * W + px;
        sD1[s] = y1i * W + px;
        sW0[s] = hy * wxA * vm;
        sW1[s] = hy * wxB * vm;
        sW2[s] = ly * wxA * vm;
        sW3[s] = ly * wxB * vm;
    }
    __syncthreads();

    const float* base = feat + (size_t)b * (size_t)(256u * HW);
    float* o = out + (size_t)lvl * LVL_STRIDE + (size_t)r * ROI_STRIDE;

    #pragma unroll 1
    for (int i = 0; i < 48; i += 2) {
        const int itemA = i * 256 + t;
        const int itemB = itemA + 256;
        const unsigned cA = (unsigned)itemA / 49u;
        const unsigned cB = (unsigned)itemB / 49u;
        const int binA = itemA - (int)cA * 49;
        const int binB = itemB - (int)cB * 49;
        const float* pA = base + (size_t)cA * HW;
        const float* pB = base + (size_t)cB * HW;

        float accA = 0.0f, accB = 0.0f;
        #pragma unroll
        for (int sub = 0; sub < 4; ++sub) {
            const int sA = sub * NBIN + binA;
            const int sB = sub * NBIN + binB;
            const f2v a0 = load_f2(pA + sD0[sA]);
            const f2v a1 = load_f2(pA + sD1[sA]);
            const f2v b0 = load_f2(pB + sD0[sB]);
            const f2v b1 = load_f2(pB + sD1[sB]);
            accA += a0.x * sW0[sA] + a0.y * sW1[sA]
                  + a1.x * sW2[sA] + a1.y * sW3[sA];
            accB += b0.x * sW0[sB] + b0.y * sW1[sB]
                  + b1.x * sW2[sB] + b1.y * sW3[sB];
        }
        o[itemA] = accA;
        o[itemB] = accB;
    }
    {
        const int item = 48 * 256 + t;
        const unsigned c = (unsigned)item / 49u;
        const int bin = item - (int)c * 49;
        const float* p = base + (size_t)c * HW;
        float acc = 0.0f;
        #pragma unroll
        for (int sub = 0; sub < 4; ++sub) {
            const int s = sub * NBIN + bin;
            const f2v a0 = load_f2(p + sD0[s]);
            const f2v a1 = load_f2(p + sD1[s]);
            acc += a0.x * sW0[s] + a0.y * sW1[s]
                 + a1.x * sW2[s] + a1.y * sW3[s];
        }
        o[item] = acc;
    }
}

extern "C" void kernel_launch(void* const* d_in, const int* in_sizes, int n_in,
                              void* d_out, int out_size, void* d_ws, size_t ws_size,
                              hipStream_t stream) {
    const float* f0    = (const float*)d_in[0];
    const float* f1    = (const float*)d_in[1];
    const float* f2    = (const float*)d_in[2];
    const float* f3    = (const float*)d_in[3];
    const float* boxes = (const float*)d_in[4];
    float* out = (float*)d_out;

    if (d_ws != nullptr && ws_size >= WS_BYTES) {
        float* w = (float*)d_ws;
        fused_to_nhwc<<<dim3(2524, 2), 256, 0, stream>>>(f0, f1, f2, f3, w);
        roi_gather_nhwc<<<dim3(1024, 4, 2), 256, 0, stream>>>(w, boxes, out);
    } else {
        dim3 grid(1024, 4);
        roi_align_all_levels<<<grid, 256, 0, stream>>>(f0, f1, f2, f3, boxes, out);
    }
}